// Round 1
// 323.467 us; speedup vs baseline: 1.0015x; 1.0015x over previous
//
#include <hip/hip_runtime.h>
#include <math.h>

#define BB 2
#define SS 2048
#define EE 2048
#define HH 16
#define KVHH 4
#define DD 128
#define GG (HH / KVHH)
#define KVN (KVHH * DD)   // 512
#define SCALE 0.08838834764831843f
// SCALE * log2(e): scores land in log2 domain -> exp2f softmax
#define QSCALE (0.08838834764831843f * 1.4426950408889634f)

typedef __attribute__((ext_vector_type(8))) short bf16x8;
typedef __attribute__((ext_vector_type(4))) float f32x4;
typedef unsigned short u16;
typedef unsigned int u32;

__device__ __forceinline__ u16 f2bf(float f) {
    union { float f; u32 u; } x; x.f = f;
    u32 r = x.u + 0x7fff + ((x.u >> 16) & 1);   // RNE
    return (u16)(r >> 16);
}
__device__ __forceinline__ u32 f2bf_pk(float a, float b) {
    return (u32)f2bf(a) | ((u32)f2bf(b) << 16);
}

__device__ __forceinline__ void gload_lds16(const void* g, void* l) {
    __builtin_amdgcn_global_load_lds(
        (const __attribute__((address_space(1))) u32*)g,
        (__attribute__((address_space(3))) u32*)l, 16, 0, 0);
}

// ---------------------------------------------------------------------------
// Fused fp32->bf16 cast of all 5 tensors. Block-granular segments, 1024 el/blk.
// ---------------------------------------------------------------------------
#define NB_X  8192      // B*S*E / 1024
#define NB_QO 4096      // E*E / 1024
#define NB_KV 1024      // KVN*E / 1024
__global__ __launch_bounds__(256) void cast_all(const float* __restrict__ x,
                                                const float* __restrict__ wq,
                                                const float* __restrict__ wk,
                                                const float* __restrict__ wv,
                                                const float* __restrict__ wo,
                                                u16* __restrict__ xb, u16* __restrict__ wqb,
                                                u16* __restrict__ wkb, u16* __restrict__ wvb,
                                                u16* __restrict__ wob) {
    int bid = blockIdx.x;
    const float* src; u16* dst; int off;
    if (bid < NB_X)                       { src = x;  dst = xb;  off = bid * 1024; }
    else if (bid < NB_X + NB_QO)          { src = wq; dst = wqb; off = (bid - NB_X) * 1024; }
    else if (bid < NB_X + NB_QO + NB_KV)  { src = wk; dst = wkb; off = (bid - NB_X - NB_QO) * 1024; }
    else if (bid < NB_X + NB_QO + 2*NB_KV){ src = wv; dst = wvb; off = (bid - NB_X - NB_QO - NB_KV) * 1024; }
    else                                  { src = wo; dst = wob; off = (bid - NB_X - NB_QO - 2*NB_KV) * 1024; }
    int i = off + threadIdx.x * 4;
    float4 v = *(const float4*)&src[i];
    ushort4 o;
    o.x = f2bf(v.x); o.y = f2bf(v.y); o.z = f2bf(v.z); o.w = f2bf(v.w);
    *(ushort4*)&dst[i] = o;
}

// ---------------------------------------------------------------------------
// m97-structure MFMA GEMM: C[M,N] = A[M,K] @ B[N,K]^T, bf16 in, fp32 acc.
// MODE 0: fp32 row-major C
// MODE 5: fused QKV epilogue (B = [Wq;Wk;Wv] concat, N=3072):
//   n<2048      -> Qg bf16 [M][2048], scaled by QSCALE
//   2048..2559  -> Kg bf16 [M][512]
//   2560..3071  -> Vt bf16 [(b*KVN + d)][S]
// ---------------------------------------------------------------------------
template <int MODE>
__global__ __launch_bounds__(256) void gemm_mfma(const u16* __restrict__ A,
                                                 const u16* __restrict__ B,
                                                 void* __restrict__ Cv,
                                                 void* __restrict__ Cv2,
                                                 void* __restrict__ Cv3,
                                                 int M, int N, int K) {
    __shared__ __align__(16) u16 As[128 * 32];
    __shared__ __align__(16) u16 Bs[128 * 32];
    const int tid  = threadIdx.x;
    const int w    = tid >> 6;
    const int lane = tid & 63;
    const int l16  = lane & 15;
    const int quad = lane >> 4;
    const int wm = (w >> 1) * 64;
    const int wn = (w & 1) * 64;
    const int m0 = blockIdx.y * 128;
    const int n0 = blockIdx.x * 128;

    const int r0 = tid >> 2,           ko0 = (tid & 3) * 8;
    const int r1 = (256 + tid) >> 2,   ko1 = (tid & 3) * 8;
    u16* ldsA0 = &As[(size_t)(w * 64) * 8];
    u16* ldsA1 = &As[(size_t)(256 + w * 64) * 8];
    u16* ldsB0 = &Bs[(size_t)(w * 64) * 8];
    u16* ldsB1 = &Bs[(size_t)(256 + w * 64) * 8];

    f32x4 acc[4][4];
#pragma unroll
    for (int i = 0; i < 4; ++i)
#pragma unroll
        for (int j = 0; j < 4; ++j) acc[i][j] = (f32x4){0.f, 0.f, 0.f, 0.f};

    for (int k0 = 0; k0 < K; k0 += 32) {
        __syncthreads();
        gload_lds16(A + (size_t)(m0 + r0) * K + k0 + ko0, ldsA0);
        gload_lds16(A + (size_t)(m0 + r1) * K + k0 + ko1, ldsA1);
        gload_lds16(B + (size_t)(n0 + r0) * K + k0 + ko0, ldsB0);
        gload_lds16(B + (size_t)(n0 + r1) * K + k0 + ko1, ldsB1);
        __syncthreads();

        bf16x8 af[4], bfr[4];
#pragma unroll
        for (int i = 0; i < 4; ++i)
            af[i] = *(const bf16x8*)&As[(wm + i * 16 + l16) * 32 + quad * 8];
#pragma unroll
        for (int j = 0; j < 4; ++j)
            bfr[j] = *(const bf16x8*)&Bs[(wn + j * 16 + l16) * 32 + quad * 8];
#pragma unroll
        for (int i = 0; i < 4; ++i)
#pragma unroll
            for (int j = 0; j < 4; ++j)
                acc[i][j] = __builtin_amdgcn_mfma_f32_16x16x32_bf16(af[i], bfr[j], acc[i][j], 0, 0, 0);
    }

    if (MODE == 0) {
        float* C = (float*)Cv;
#pragma unroll
        for (int i = 0; i < 4; ++i)
#pragma unroll
            for (int j = 0; j < 4; ++j)
#pragma unroll
                for (int reg = 0; reg < 4; ++reg)
                    C[(size_t)(m0 + wm + i * 16 + quad * 4 + reg) * N + n0 + wn + j * 16 + l16] =
                        acc[i][j][reg];
    } else {   // MODE 5
        if (n0 < 2048) {
            u16* C = (u16*)Cv;   // Qg [M][2048], QSCALE folded in
#pragma unroll
            for (int i = 0; i < 4; ++i)
#pragma unroll
                for (int j = 0; j < 4; ++j)
#pragma unroll
                    for (int reg = 0; reg < 4; ++reg)
                        C[(size_t)(m0 + wm + i * 16 + quad * 4 + reg) * 2048 + n0 + wn + j * 16 + l16] =
                            f2bf(acc[i][j][reg] * QSCALE);
        } else if (n0 < 2560) {
            u16* C = (u16*)Cv2;  // Kg [M][512]
            const int nb = n0 - 2048;
#pragma unroll
            for (int i = 0; i < 4; ++i)
#pragma unroll
                for (int j = 0; j < 4; ++j)
#pragma unroll
                    for (int reg = 0; reg < 4; ++reg)
                        C[(size_t)(m0 + wm + i * 16 + quad * 4 + reg) * KVN + nb + wn + j * 16 + l16] =
                            f2bf(acc[i][j][reg]);
        } else {
            u16* C2 = (u16*)Cv3;  // Vt [(b*KVN + d)][S]
            const int db = n0 - 2560;
#pragma unroll
            for (int i = 0; i < 4; ++i) {
                const int m = m0 + wm + i * 16 + quad * 4;
                const int bb = m >> 11;
                const int s  = m & (SS - 1);
#pragma unroll
                for (int j = 0; j < 4; ++j) {
                    const int d = db + wn + j * 16 + l16;
                    ushort4 p;
                    p.x = f2bf(acc[i][j][0]); p.y = f2bf(acc[i][j][1]);
                    p.z = f2bf(acc[i][j][2]); p.w = f2bf(acc[i][j][3]);
                    *(ushort4*)&C2[((size_t)(bb * KVN + d)) * SS + s] = p;
                }
            }
        }
    }
}

// ---------------------------------------------------------------------------
// Flash-style causal GQA attention, bf16 MFMA.
// RESTRUCTURED for occupancy: Q-tile 64 x K-tile 32, LDS 36 KB -> 4 blocks/CU
// (was 128x64, 80 KB, 2 blocks/CU, 12.5% measured occupancy).
// Grid 1024: slice-per-XCD map (xcd = bid&7 -> (b,kvh); 1 MB KV set per XCD L2)
// and the 4 blocks co-resident on a CU share one head with balanced causal
// lengths {r, r+8, 31-r, 23-r} (exactly 132 half-tiles per CU).
// Each wave owns 16 q-rows; K/V double-buffered via global_load_lds with
// XOR-swizzled layouts (3-bit key for K rows of 16 chunks, 2-bit key
// (r^(r>>2))&3 for V/P rows of 4 chunks) -> b128 reads at inherent minimum.
// T13 defer-max (THR=8 in log2 domain) skips the O-rescale pass when no row's
// max grew past m+8.
// ---------------------------------------------------------------------------
__global__ __launch_bounds__(256, 4) void attn_mfma(const u16* __restrict__ Qg,
                                                    const u16* __restrict__ Kg,
                                                    const u16* __restrict__ VtG,
                                                    u16* __restrict__ ctx) {
    __shared__ __align__(16) u16 Ks[2][32 * 128];    // 2 x 8 KB
    __shared__ __align__(16) u16 Vt[2][128 * 32];    // 2 x 8 KB
    __shared__ __align__(16) u16 Ps[64 * 32];        // 4 KB

    const int tid  = threadIdx.x;
    const int w    = tid >> 6;
    const int lane = tid & 63;
    const int l16  = lane & 15;
    const int quad = lane >> 4;
    const int sw   = l16 & 7;                     // K swizzle key (3-bit)
    const int vsw  = (l16 ^ (l16 >> 2)) & 3;      // V / P swizzle key (2-bit)

    // slice-per-XCD task map + per-CU balanced qc
    const int f   = blockIdx.x;
    const int xcd = f & 7;
    const int idx = f >> 3;          // 0..127
    const int b   = xcd >> 2;
    const int kvh = xcd & 3;
    const int h   = kvh * GG + (idx & 3);
    const int rr  = idx >> 2;        // 0..31
    const int jj  = rr & 15;
    const int qc  = (rr >> 4) ? (31 - jj) : jj;
    const int q0  = qc * 64;

    const size_t kgbase = (size_t)(b * SS) * KVN + kvh * DD;
    const size_t vgbase = (size_t)(b * KVN + kvh * DD) * SS;

    const int myq   = q0 + w * 16 + l16;   // this lane's q-row
    const int wqmax = q0 + w * 16 + 15;    // wave's max q-row
    const int prow  = w * 16 + l16;        // P row within tile

    // ---- Q fragments direct from global (wave's 16 rows) ----
    bf16x8 Qa[4];
#pragma unroll
    for (int kd = 0; kd < 4; ++kd)
        Qa[kd] = *(const bf16x8*)(Qg + (size_t)(b * SS + myq) * EE
                                  + h * DD + kd * 32 + quad * 8);

    float m_i = -INFINITY;
    float l_i = 0.f;
    f32x4 acc_o[8];
#pragma unroll
    for (int dt = 0; dt < 8; ++dt) acc_o[dt] = (f32x4){0.f, 0.f, 0.f, 0.f};

    const int ktlast = 2 * qc + 1;

    // ---- swizzled async stage of K (32x128) and Vt (128x32) tiles ----
    auto stage = [&](int kt, int buf) {
#pragma unroll
        for (int it = 0; it < 2; ++it) {
            int ci = it * 256 + tid;          // K chunk slot (16B units), 512 total
            int r = ci >> 4, pp = ci & 15;
            int c = (pp & 8) | ((pp ^ (r & 7)) & 7);   // source chunk for this slot
            gload_lds16(Kg + kgbase + (size_t)(kt * 32 + r) * KVN + c * 8,
                        &Ks[buf][(size_t)(it * 256 + (tid & 192)) * 8]);
        }
#pragma unroll
        for (int it = 0; it < 2; ++it) {
            int ci = it * 256 + tid;          // V chunk slot, 512 total
            int r = ci >> 2, pp = ci & 3;
            int c = pp ^ ((r ^ (r >> 2)) & 3);
            gload_lds16(VtG + vgbase + (size_t)r * SS + kt * 32 + c * 8,
                        &Vt[buf][(size_t)(it * 256 + (tid & 192)) * 8]);
        }
    };

    stage(0, 0);
    int pbuf = 0;

    for (int kt = 0; kt <= ktlast; ++kt) {
        __syncthreads();                 // drains DMA for buf[pbuf]; prev readers done
        if (kt < ktlast) stage(kt + 1, pbuf ^ 1);   // overlaps entire compute phase

        const u16* kb_base = Ks[pbuf];
        const u16* vb_base = Vt[pbuf];
        const bool skipw = (kt * 32 > wqmax);   // wave fully masked on this k-tile

        if (!skipw) {
            // ---- S^T = K Q^T : lane q=l16, k = kt*32 + kkt*16 + quad*4 + reg ----
            f32x4 sc[2];
            sc[0] = (f32x4){0.f, 0.f, 0.f, 0.f};
            sc[1] = (f32x4){0.f, 0.f, 0.f, 0.f};
#pragma unroll
            for (int kkt = 0; kkt < 2; ++kkt) {
                const int R = kkt * 16 + l16;
                bf16x8 kb[4];
#pragma unroll
                for (int kd = 0; kd < 4; ++kd) {
                    int c = kd * 4 + quad;
                    int pp = (c & 8) | ((c ^ sw) & 7);
                    kb[kd] = *(const bf16x8*)&kb_base[(R * 16 + pp) * 8];
                }
#pragma unroll
                for (int kd = 0; kd < 4; ++kd)
                    sc[kkt] = __builtin_amdgcn_mfma_f32_16x16x32_bf16(kb[kd], Qa[kd], sc[kkt], 0, 0, 0);
            }

            // ---- causal mask on diagonal tiles ----
            if (kt >= 2 * qc) {
                const int kb0 = kt * 32 + quad * 4;
#pragma unroll
                for (int kkt = 0; kkt < 2; ++kkt)
#pragma unroll
                    for (int reg = 0; reg < 4; ++reg)
                        if (kb0 + kkt * 16 + reg > myq) sc[kkt][reg] = -INFINITY;
            }

            // ---- per-lane online softmax (log2 domain), defer-max THR=8 ----
            float rowmax = -INFINITY;
#pragma unroll
            for (int kkt = 0; kkt < 2; ++kkt)
#pragma unroll
                for (int reg = 0; reg < 4; ++reg)
                    rowmax = fmaxf(rowmax, sc[kkt][reg]);
            rowmax = fmaxf(rowmax, __shfl_xor(rowmax, 16, 64));
            rowmax = fmaxf(rowmax, __shfl_xor(rowmax, 32, 64));

            if (__any(rowmax > m_i + 8.0f)) {        // rescale pass (rare after warmup)
                float mnew = fmaxf(m_i, rowmax);
                float al = exp2f(m_i - mnew);
                m_i = mnew;
                l_i *= al;
#pragma unroll
                for (int dt = 0; dt < 8; ++dt)
#pragma unroll
                    for (int reg = 0; reg < 4; ++reg)
                        acc_o[dt][reg] *= al;
            }

            float rsum = 0.f;
#pragma unroll
            for (int kkt = 0; kkt < 2; ++kkt)
#pragma unroll
                for (int reg = 0; reg < 4; ++reg) {
                    float p = exp2f(sc[kkt][reg] - m_i);   // bounded by 2^8
                    sc[kkt][reg] = p;
                    rsum += p;
                }
            rsum += __shfl_xor(rsum, 16, 64);
            rsum += __shfl_xor(rsum, 32, 64);
            l_i += rsum;

            // ---- swizzled packed P^T write (8-B halves of 16-B chunks) ----
#pragma unroll
            for (int kkt = 0; kkt < 2; ++kkt) {
                int ch = (kkt * 2 + (quad >> 1)) ^ vsw;
                uint2 pk;
                pk.x = f2bf_pk(sc[kkt][0], sc[kkt][1]);
                pk.y = f2bf_pk(sc[kkt][2], sc[kkt][3]);
                *(uint2*)&Ps[(prow * 4 + ch) * 8 + (quad & 1) * 4] = pk;
            }
            // no barrier: each wave reads only its own Ps rows (lgkmcnt orders it)

            // ---- O^T += V^T P^T (single 32-k slice) ----
            bf16x8 pb = *(const bf16x8*)&Ps[(prow * 4 + (quad ^ vsw)) * 8];
#pragma unroll
            for (int dt = 0; dt < 8; ++dt) {
                bf16x8 va = *(const bf16x8*)&vb_base[((dt * 16 + l16) * 4 + (quad ^ vsw)) * 8];
                acc_o[dt] = __builtin_amdgcn_mfma_f32_16x16x32_bf16(va, pb, acc_o[dt], 0, 0, 0);
            }
        }
        pbuf ^= 1;
    }

    // ---- epilogue: packed ushort4 stores, lane q=l16, d=dt*16+quad*4+reg ----
    {
        const float linv = 1.f / l_i;
        u16* dst = ctx + (size_t)(b * SS + myq) * EE + h * DD;
#pragma unroll
        for (int dt = 0; dt < 8; ++dt) {
            ushort4 o;
            o.x = f2bf(acc_o[dt][0] * linv);
            o.y = f2bf(acc_o[dt][1] * linv);
            o.z = f2bf(acc_o[dt][2] * linv);
            o.w = f2bf(acc_o[dt][3] * linv);
            *(ushort4*)&dst[dt * 16 + quad * 4] = o;
        }
    }
}

// ---------------------------------------------------------------------------
extern "C" void kernel_launch(void* const* d_in, const int* in_sizes, int n_in,
                              void* d_out, int out_size, void* d_ws, size_t ws_size,
                              hipStream_t stream) {
    const float* x  = (const float*)d_in[0];
    const float* Wq = (const float*)d_in[1];
    const float* Wk = (const float*)d_in[2];
    const float* Wv = (const float*)d_in[3];
    const float* Wo = (const float*)d_in[4];
    float* out = (float*)d_out;

    const int M = BB * SS;                        // 4096
    u16* xb  = (u16*)d_ws;                        // M*E
    u16* Wqb = xb  + (size_t)M * EE;              // E*E   } contiguous ->
    u16* Wkb = Wqb + (size_t)EE * EE;             // KVN*E }  single 3072-row
    u16* Wvb = Wkb + (size_t)KVN * EE;            // KVN*E }  B matrix
    u16* Wob = Wvb + (size_t)KVN * EE;             // E*E
    u16* Qg  = Wob + (size_t)EE * EE;             // M*E (pre-scaled by QSCALE)
    u16* Kg  = Qg  + (size_t)M * EE;              // M*KVN
    u16* VtG = Kg  + (size_t)M * KVN;             // M*KVN (transposed)
    u16* ctx = VtG + (size_t)M * KVN;             // M*E

    dim3 blk(256);
    cast_all<<<dim3(NB_X + NB_QO + 2 * NB_KV + NB_QO), blk, 0, stream>>>(
        x, Wq, Wk, Wv, Wo, xb, Wqb, Wkb, Wvb, Wob);

    // fused QKV projection: B = [Wq;Wk;Wv] (3072 x 2048)
    gemm_mfma<5><<<dim3(3072 / 128, M / 128), blk, 0, stream>>>(
        xb, Wqb, Qg, Kg, VtG, M, 3072, EE);
    attn_mfma<<<dim3(1024), blk, 0, stream>>>(Qg, Kg, VtG, ctx);
    gemm_mfma<0><<<dim3(EE / 128, M / 128), blk, 0, stream>>>(
        ctx, Wob, out, nullptr, nullptr, M, EE, EE);
}

// Round 2
// 316.634 us; speedup vs baseline: 1.0231x; 1.0216x over previous
//
#include <hip/hip_runtime.h>
#include <math.h>

#define BB 2
#define SS 2048
#define EE 2048
#define HH 16
#define KVHH 4
#define DD 128
#define GG (HH / KVHH)
#define KVN (KVHH * DD)   // 512
#define SCALE 0.08838834764831843f
// SCALE * log2(e): scores land in log2 domain -> exp2f softmax
#define QSCALE (0.08838834764831843f * 1.4426950408889634f)

typedef __attribute__((ext_vector_type(8))) short bf16x8;
typedef __attribute__((ext_vector_type(4))) float f32x4;
typedef unsigned short u16;
typedef unsigned int u32;

__device__ __forceinline__ u16 f2bf(float f) {
    union { float f; u32 u; } x; x.f = f;
    u32 r = x.u + 0x7fff + ((x.u >> 16) & 1);   // RNE
    return (u16)(r >> 16);
}
__device__ __forceinline__ u32 f2bf_pk(float a, float b) {
    return (u32)f2bf(a) | ((u32)f2bf(b) << 16);
}
// HW packed f32->bf16 (RNE), 1 instr for 2 values: lo=bf16(a), hi=bf16(b)
__device__ __forceinline__ u32 cvtpk_bf16(float a, float b) {
    u32 r;
    asm("v_cvt_pk_bf16_f32 %0, %1, %2" : "=v"(r) : "v"(a), "v"(b));
    return r;
}

__device__ __forceinline__ void gload_lds16(const void* g, void* l) {
    __builtin_amdgcn_global_load_lds(
        (const __attribute__((address_space(1))) u32*)g,
        (__attribute__((address_space(3))) u32*)l, 16, 0, 0);
}

// ---------------------------------------------------------------------------
// Fused fp32->bf16 cast of all 5 tensors. Block-granular segments, 1024 el/blk.
// ---------------------------------------------------------------------------
#define NB_X  8192      // B*S*E / 1024
#define NB_QO 4096      // E*E / 1024
#define NB_KV 1024      // KVN*E / 1024
__global__ __launch_bounds__(256) void cast_all(const float* __restrict__ x,
                                                const float* __restrict__ wq,
                                                const float* __restrict__ wk,
                                                const float* __restrict__ wv,
                                                const float* __restrict__ wo,
                                                u16* __restrict__ xb, u16* __restrict__ wqb,
                                                u16* __restrict__ wkb, u16* __restrict__ wvb,
                                                u16* __restrict__ wob) {
    int bid = blockIdx.x;
    const float* src; u16* dst; int off;
    if (bid < NB_X)                       { src = x;  dst = xb;  off = bid * 1024; }
    else if (bid < NB_X + NB_QO)          { src = wq; dst = wqb; off = (bid - NB_X) * 1024; }
    else if (bid < NB_X + NB_QO + NB_KV)  { src = wk; dst = wkb; off = (bid - NB_X - NB_QO) * 1024; }
    else if (bid < NB_X + NB_QO + 2*NB_KV){ src = wv; dst = wvb; off = (bid - NB_X - NB_QO - NB_KV) * 1024; }
    else                                  { src = wo; dst = wob; off = (bid - NB_X - NB_QO - 2*NB_KV) * 1024; }
    int i = off + threadIdx.x * 4;
    float4 v = *(const float4*)&src[i];
    ushort4 o;
    o.x = f2bf(v.x); o.y = f2bf(v.y); o.z = f2bf(v.z); o.w = f2bf(v.w);
    *(ushort4*)&dst[i] = o;
}

// ---------------------------------------------------------------------------
// m97-structure MFMA GEMM: C[M,N] = A[M,K] @ B[N,K]^T, bf16 in, fp32 acc.
// MODE 0: fp32 row-major C
// MODE 5: fused QKV epilogue (B = [Wq;Wk;Wv] concat, N=3072):
//   n<2048      -> Qg bf16 [M][2048], scaled by QSCALE
//   2048..2559  -> Kg bf16 [M][512]
//   2560..3071  -> Vt bf16 [(b*KVN + d)][S]
// ---------------------------------------------------------------------------
template <int MODE>
__global__ __launch_bounds__(256) void gemm_mfma(const u16* __restrict__ A,
                                                 const u16* __restrict__ B,
                                                 void* __restrict__ Cv,
                                                 void* __restrict__ Cv2,
                                                 void* __restrict__ Cv3,
                                                 int M, int N, int K) {
    __shared__ __align__(16) u16 As[128 * 32];
    __shared__ __align__(16) u16 Bs[128 * 32];
    const int tid  = threadIdx.x;
    const int w    = tid >> 6;
    const int lane = tid & 63;
    const int l16  = lane & 15;
    const int quad = lane >> 4;
    const int wm = (w >> 1) * 64;
    const int wn = (w & 1) * 64;
    const int m0 = blockIdx.y * 128;
    const int n0 = blockIdx.x * 128;

    const int r0 = tid >> 2,           ko0 = (tid & 3) * 8;
    const int r1 = (256 + tid) >> 2,   ko1 = (tid & 3) * 8;
    u16* ldsA0 = &As[(size_t)(w * 64) * 8];
    u16* ldsA1 = &As[(size_t)(256 + w * 64) * 8];
    u16* ldsB0 = &Bs[(size_t)(w * 64) * 8];
    u16* ldsB1 = &Bs[(size_t)(256 + w * 64) * 8];

    f32x4 acc[4][4];
#pragma unroll
    for (int i = 0; i < 4; ++i)
#pragma unroll
        for (int j = 0; j < 4; ++j) acc[i][j] = (f32x4){0.f, 0.f, 0.f, 0.f};

    for (int k0 = 0; k0 < K; k0 += 32) {
        __syncthreads();
        gload_lds16(A + (size_t)(m0 + r0) * K + k0 + ko0, ldsA0);
        gload_lds16(A + (size_t)(m0 + r1) * K + k0 + ko1, ldsA1);
        gload_lds16(B + (size_t)(n0 + r0) * K + k0 + ko0, ldsB0);
        gload_lds16(B + (size_t)(n0 + r1) * K + k0 + ko1, ldsB1);
        __syncthreads();

        bf16x8 af[4], bfr[4];
#pragma unroll
        for (int i = 0; i < 4; ++i)
            af[i] = *(const bf16x8*)&As[(wm + i * 16 + l16) * 32 + quad * 8];
#pragma unroll
        for (int j = 0; j < 4; ++j)
            bfr[j] = *(const bf16x8*)&Bs[(wn + j * 16 + l16) * 32 + quad * 8];
#pragma unroll
        for (int i = 0; i < 4; ++i)
#pragma unroll
            for (int j = 0; j < 4; ++j)
                acc[i][j] = __builtin_amdgcn_mfma_f32_16x16x32_bf16(af[i], bfr[j], acc[i][j], 0, 0, 0);
    }

    if (MODE == 0) {
        float* C = (float*)Cv;
#pragma unroll
        for (int i = 0; i < 4; ++i)
#pragma unroll
            for (int j = 0; j < 4; ++j)
#pragma unroll
                for (int reg = 0; reg < 4; ++reg)
                    C[(size_t)(m0 + wm + i * 16 + quad * 4 + reg) * N + n0 + wn + j * 16 + l16] =
                        acc[i][j][reg];
    } else {   // MODE 5
        if (n0 < 2048) {
            u16* C = (u16*)Cv;   // Qg [M][2048], QSCALE folded in
#pragma unroll
            for (int i = 0; i < 4; ++i)
#pragma unroll
                for (int j = 0; j < 4; ++j)
#pragma unroll
                    for (int reg = 0; reg < 4; ++reg)
                        C[(size_t)(m0 + wm + i * 16 + quad * 4 + reg) * 2048 + n0 + wn + j * 16 + l16] =
                            f2bf(acc[i][j][reg] * QSCALE);
        } else if (n0 < 2560) {
            u16* C = (u16*)Cv2;  // Kg [M][512]
            const int nb = n0 - 2048;
#pragma unroll
            for (int i = 0; i < 4; ++i)
#pragma unroll
                for (int j = 0; j < 4; ++j)
#pragma unroll
                    for (int reg = 0; reg < 4; ++reg)
                        C[(size_t)(m0 + wm + i * 16 + quad * 4 + reg) * KVN + nb + wn + j * 16 + l16] =
                            f2bf(acc[i][j][reg]);
        } else {
            u16* C2 = (u16*)Cv3;  // Vt [(b*KVN + d)][S]
            const int db = n0 - 2560;
#pragma unroll
            for (int i = 0; i < 4; ++i) {
                const int m = m0 + wm + i * 16 + quad * 4;
                const int bb = m >> 11;
                const int s  = m & (SS - 1);
#pragma unroll
                for (int j = 0; j < 4; ++j) {
                    const int d = db + wn + j * 16 + l16;
                    ushort4 p;
                    p.x = f2bf(acc[i][j][0]); p.y = f2bf(acc[i][j][1]);
                    p.z = f2bf(acc[i][j][2]); p.w = f2bf(acc[i][j][3]);
                    *(ushort4*)&C2[((size_t)(bb * KVN + d)) * SS + s] = p;
                }
            }
        }
    }
}

// ---------------------------------------------------------------------------
// Flash-style causal GQA attention, bf16 MFMA, Q-tile 128 x K-tile 64.
// Round-0 geometry (32 q-rows/wave: minimal LDS read amplification, 8B/score)
// with the softmax VALU chain cut down:
//  - v_cvt_pk_bf16_f32 (HW RNE) for P-pack and epilogue (8 instrs vs ~40)
//  - T13 vote-gated rescale: per-lane rowmax + __any(rowmax > m+8); the
//    cross-lane max shuffles and the 32-mult O-rescale only run when the
//    vote fires (rare in steady state). exp2 args bounded by 8 -> P <= 256.
//  - deferred l: per-lane partial sum, cross-lane reduce once in epilogue
//    (alpha is quad-uniform so scaling commutes with the group sum)
//  - s_setprio(1) around QK / PV MFMA clusters (T5)
// K/V staged via global_load_lds into XOR-swizzled unpadded LDS, double-
// buffered; P swizzled the same way. LDS = 80 KB -> 2 blocks/CU.
// ---------------------------------------------------------------------------
__global__ __launch_bounds__(256, 2) void attn_mfma(const u16* __restrict__ Qg,
                                                    const u16* __restrict__ Kg,
                                                    const u16* __restrict__ VtG,
                                                    u16* __restrict__ ctx) {
    __shared__ __align__(16) u16 Ks[2][64 * 128];    // 2 x 16 KB
    __shared__ __align__(16) u16 Vt[2][128 * 64];    // 2 x 16 KB
    __shared__ __align__(16) u16 Ps[128 * 64];       // 16 KB

    const int tid  = threadIdx.x;
    const int w    = tid >> 6;
    const int lane = tid & 63;
    const int l16  = lane & 15;
    const int quad = lane >> 4;
    const int sw   = l16 & 7;            // swizzle key for all fragment rows

    // balanced task map: blocks f and f+256 get qc summing to 15
    const int f    = blockIdx.x;
    const int half = f >> 8;
    const int u    = f & 255;
    const int h    = u & 15;
    const int w2   = u >> 4;
    const int b    = w2 & 1;
    const int j    = w2 >> 1;                  // 0..7
    const int qc   = half ? (15 - j) : j;      // 0..15
    const int kvh  = h / GG;
    const int q0   = qc * 128;

    const size_t kgbase = (size_t)(b * SS) * KVN + kvh * DD;
    const size_t vgbase = (size_t)(b * KVN + kvh * DD) * SS;

    // ---- Q fragments direct from global ----
    bf16x8 Qa[2][4];
#pragma unroll
    for (int mi = 0; mi < 2; ++mi)
#pragma unroll
        for (int kd = 0; kd < 4; ++kd)
            Qa[mi][kd] = *(const bf16x8*)(Qg + (size_t)(b * SS + q0 + mi * 64 + w * 16 + l16) * EE
                                          + h * DD + kd * 32 + quad * 8);

    float m_i[2] = {-INFINITY, -INFINITY};
    float l_i[2] = {0.f, 0.f};          // per-lane partials, reduced in epilogue
    f32x4 acc_o[2][8];
#pragma unroll
    for (int mi = 0; mi < 2; ++mi)
#pragma unroll
        for (int dt = 0; dt < 8; ++dt) acc_o[mi][dt] = (f32x4){0.f, 0.f, 0.f, 0.f};

    const int ktlast = 2 * qc + 1;
    const int myq[2] = { q0 + w * 16 + l16, q0 + 64 + w * 16 + l16 };

    // ---- swizzled async stage of K (64x128) and Vt (128x64) tiles ----
    auto stage = [&](int kt, int buf) {
#pragma unroll
        for (int it = 0; it < 4; ++it) {
            int ci = it * 256 + tid;          // chunk position in LDS (16B units)
            int r = ci >> 4, pp = ci & 15;
            int c = (pp & 8) | ((pp ^ r) & 7);   // global chunk that belongs here
            gload_lds16(Kg + kgbase + (size_t)(kt * 64 + r) * KVN + c * 8,
                        &Ks[buf][(size_t)(it * 256 + (tid & 192)) * 8]);
        }
#pragma unroll
        for (int it = 0; it < 4; ++it) {
            int ci = it * 256 + tid;
            int r = ci >> 3, pp = ci & 7;
            int c = (pp ^ r) & 7;
            gload_lds16(VtG + vgbase + (size_t)r * SS + kt * 64 + c * 8,
                        &Vt[buf][(size_t)(it * 256 + (tid & 192)) * 8]);
        }
    };

    stage(0, 0);
    int pbuf = 0;

    for (int kt = 0; kt <= ktlast; ++kt) {
        __syncthreads();                 // drains DMA for buf[pbuf]; prev readers done
        if (kt < ktlast) stage(kt + 1, pbuf ^ 1);   // overlaps entire compute phase

        const u16* kb_base = Ks[pbuf];
        const u16* vb_base = Vt[pbuf];
        const bool skip0 = (kt == ktlast);   // mi=0 rows fully masked on last k-tile

        // ---- S^T = K Q^T : lane q=l16, k = kt*64 + kkt*16 + quad*4 + reg ----
        f32x4 sc[2][4];
#pragma unroll
        for (int mi = 0; mi < 2; ++mi)
#pragma unroll
            for (int kkt = 0; kkt < 4; ++kkt) sc[mi][kkt] = (f32x4){0.f, 0.f, 0.f, 0.f};
        __builtin_amdgcn_s_setprio(1);
#pragma unroll
        for (int kkt = 0; kkt < 4; ++kkt) {
            const int R = kkt * 16 + l16;
            bf16x8 kb[4];
#pragma unroll
            for (int kd = 0; kd < 4; ++kd) {
                int c = kd * 4 + quad;
                int pp = (c & 8) | ((c ^ sw) & 7);
                kb[kd] = *(const bf16x8*)&kb_base[(R * 16 + pp) * 8];
            }
#pragma unroll
            for (int kd = 0; kd < 4; ++kd)
                sc[1][kkt] = __builtin_amdgcn_mfma_f32_16x16x32_bf16(kb[kd], Qa[1][kd], sc[1][kkt], 0, 0, 0);
            if (!skip0)
#pragma unroll
                for (int kd = 0; kd < 4; ++kd)
                    sc[0][kkt] = __builtin_amdgcn_mfma_f32_16x16x32_bf16(kb[kd], Qa[0][kd], sc[0][kkt], 0, 0, 0);
        }
        __builtin_amdgcn_s_setprio(0);

        // ---- per-lane online softmax (log2 domain), vote-gated rescale ----
#pragma unroll
        for (int mi = 0; mi < 2; ++mi) {
            if (mi == 0 && skip0) continue;
            const bool diag = (kt == 2 * qc + mi);
            if (diag) {
                const int kb0 = kt * 64 + quad * 4;
#pragma unroll
                for (int kkt = 0; kkt < 4; ++kkt)
#pragma unroll
                    for (int reg = 0; reg < 4; ++reg)
                        if (kb0 + kkt * 16 + reg > myq[mi]) sc[mi][kkt][reg] = -INFINITY;
            }
            // per-lane rowmax only (max3-friendly triples); no shuffles here
            float rowmax = -INFINITY;
#pragma unroll
            for (int kkt = 0; kkt < 4; ++kkt)
                rowmax = fmaxf(rowmax,
                               fmaxf(fmaxf(sc[mi][kkt][0], sc[mi][kkt][1]),
                                     fmaxf(sc[mi][kkt][2], sc[mi][kkt][3])));

            if (__any(rowmax > m_i[mi] + 8.0f)) {   // wave-uniform branch, rare
                float gmax = fmaxf(rowmax, __shfl_xor(rowmax, 16, 64));
                gmax = fmaxf(gmax, __shfl_xor(gmax, 32, 64));
                float mnew = fmaxf(m_i[mi], gmax);
                float al = exp2f(m_i[mi] - mnew);
                m_i[mi] = mnew;
                l_i[mi] *= al;
#pragma unroll
                for (int dt = 0; dt < 8; ++dt)
#pragma unroll
                    for (int reg = 0; reg < 4; ++reg)
                        acc_o[mi][dt][reg] *= al;
            }

            float rsum = 0.f;
#pragma unroll
            for (int kkt = 0; kkt < 4; ++kkt)
#pragma unroll
                for (int reg = 0; reg < 4; ++reg) {
                    float p = exp2f(sc[mi][kkt][reg] - m_i[mi]);   // bounded by 2^8
                    sc[mi][kkt][reg] = p;
                    rsum += p;
                }
            l_i[mi] += rsum;            // per-lane partial; reduced in epilogue

            // swizzled packed P^T write via HW cvt_pk (8-B halves of 16-B chunks)
            const int prow = mi * 64 + w * 16 + l16;
#pragma unroll
            for (int kkt = 0; kkt < 4; ++kkt) {
                int ch = (kkt * 2 + (quad >> 1)) ^ sw;
                uint2 pk;
                pk.x = cvtpk_bf16(sc[mi][kkt][0], sc[mi][kkt][1]);
                pk.y = cvtpk_bf16(sc[mi][kkt][2], sc[mi][kkt][3]);
                *(uint2*)&Ps[(prow * 8 + ch) * 8 + (quad & 1) * 4] = pk;
            }
        }
        // no barrier: each wave reads only its own Ps rows (lgkmcnt orders it)

        // ---- O^T += V^T P^T ----
        __builtin_amdgcn_s_setprio(1);
#pragma unroll
        for (int ks = 0; ks < 2; ++ks) {
            const int pc = (ks * 4 + quad) ^ sw;
            bf16x8 pb1 = *(const bf16x8*)&Ps[((64 + w * 16 + l16) * 8 + pc) * 8];
            bf16x8 pb0;
            if (!skip0) pb0 = *(const bf16x8*)&Ps[((w * 16 + l16) * 8 + pc) * 8];
#pragma unroll
            for (int dt = 0; dt < 8; ++dt) {
                bf16x8 va = *(const bf16x8*)&vb_base[((dt * 16 + l16) * 8 + pc) * 8];
                acc_o[1][dt] = __builtin_amdgcn_mfma_f32_16x16x32_bf16(va, pb1, acc_o[1][dt], 0, 0, 0);
                if (!skip0)
                    acc_o[0][dt] = __builtin_amdgcn_mfma_f32_16x16x32_bf16(va, pb0, acc_o[0][dt], 0, 0, 0);
            }
        }
        __builtin_amdgcn_s_setprio(0);
        pbuf ^= 1;
    }

    // ---- epilogue: reduce l across quad group, packed uint2 stores ----
#pragma unroll
    for (int mi = 0; mi < 2; ++mi) {
        float lt = l_i[mi];
        lt += __shfl_xor(lt, 16, 64);
        lt += __shfl_xor(lt, 32, 64);
        const float linv = 1.f / lt;
        u16* dst = ctx + (size_t)(b * SS + myq[mi]) * EE + h * DD;
#pragma unroll
        for (int dt = 0; dt < 8; ++dt) {
            uint2 o;
            o.x = cvtpk_bf16(acc_o[mi][dt][0] * linv, acc_o[mi][dt][1] * linv);
            o.y = cvtpk_bf16(acc_o[mi][dt][2] * linv, acc_o[mi][dt][3] * linv);
            *(uint2*)&dst[dt * 16 + quad * 4] = o;
        }
    }
}

// ---------------------------------------------------------------------------
extern "C" void kernel_launch(void* const* d_in, const int* in_sizes, int n_in,
                              void* d_out, int out_size, void* d_ws, size_t ws_size,
                              hipStream_t stream) {
    const float* x  = (const float*)d_in[0];
    const float* Wq = (const float*)d_in[1];
    const float* Wk = (const float*)d_in[2];
    const float* Wv = (const float*)d_in[3];
    const float* Wo = (const float*)d_in[4];
    float* out = (float*)d_out;

    const int M = BB * SS;                        // 4096
    u16* xb  = (u16*)d_ws;                        // M*E
    u16* Wqb = xb  + (size_t)M * EE;              // E*E   } contiguous ->
    u16* Wkb = Wqb + (size_t)EE * EE;             // KVN*E }  single 3072-row
    u16* Wvb = Wkb + (size_t)KVN * EE;            // KVN*E }  B matrix
    u16* Wob = Wvb + (size_t)KVN * EE;            // E*E
    u16* Qg  = Wob + (size_t)EE * EE;             // M*E (pre-scaled by QSCALE)
    u16* Kg  = Qg  + (size_t)M * EE;              // M*KVN
    u16* VtG = Kg  + (size_t)M * KVN;             // M*KVN (transposed)
    u16* ctx = VtG + (size_t)M * KVN;             // M*E

    dim3 blk(256);
    cast_all<<<dim3(NB_X + NB_QO + 2 * NB_KV + NB_QO), blk, 0, stream>>>(
        x, Wq, Wk, Wv, Wo, xb, Wqb, Wkb, Wvb, Wob);

    // fused QKV projection: B = [Wq;Wk;Wv] (3072 x 2048)
    gemm_mfma<5><<<dim3(3072 / 128, M / 128), blk, 0, stream>>>(
        xb, Wqb, Qg, Kg, VtG, M, 3072, EE);
    attn_mfma<<<dim3(512), blk, 0, stream>>>(Qg, Kg, VtG, ctx);
    gemm_mfma<0><<<dim3(EE / 128, M / 128), blk, 0, stream>>>(
        ctx, Wob, out, nullptr, nullptr, M, EE, EE);
}

// Round 3
// 311.826 us; speedup vs baseline: 1.0389x; 1.0154x over previous
//
#include <hip/hip_runtime.h>
#include <math.h>

#define BB 2
#define SS 2048
#define EE 2048
#define HH 16
#define KVHH 4
#define DD 128
#define GG (HH / KVHH)
#define KVN (KVHH * DD)   // 512
#define SCALE 0.08838834764831843f
// SCALE * log2(e): scores land in log2 domain -> exp2f softmax
#define QSCALE (0.08838834764831843f * 1.4426950408889634f)

typedef __attribute__((ext_vector_type(8))) short bf16x8;
typedef __attribute__((ext_vector_type(4))) float f32x4;
typedef unsigned short u16;
typedef unsigned int u32;

__device__ __forceinline__ u16 f2bf(float f) {
    union { float f; u32 u; } x; x.f = f;
    u32 r = x.u + 0x7fff + ((x.u >> 16) & 1);   // RNE
    return (u16)(r >> 16);
}
// HW packed f32->bf16 (RNE), 1 instr for 2 values: lo=bf16(a), hi=bf16(b)
__device__ __forceinline__ u32 cvtpk_bf16(float a, float b) {
    u32 r;
    asm("v_cvt_pk_bf16_f32 %0, %1, %2" : "=v"(r) : "v"(a), "v"(b));
    return r;
}

__device__ __forceinline__ void gload_lds16(const void* g, void* l) {
    __builtin_amdgcn_global_load_lds(
        (const __attribute__((address_space(1))) u32*)g,
        (__attribute__((address_space(3))) u32*)l, 16, 0, 0);
}

// ---------------------------------------------------------------------------
// Fused fp32->bf16 cast of all 5 tensors. Block-granular segments, 1024 el/blk.
// ---------------------------------------------------------------------------
#define NB_X  8192      // B*S*E / 1024
#define NB_QO 4096      // E*E / 1024
#define NB_KV 1024      // KVN*E / 1024
__global__ __launch_bounds__(256) void cast_all(const float* __restrict__ x,
                                                const float* __restrict__ wq,
                                                const float* __restrict__ wk,
                                                const float* __restrict__ wv,
                                                const float* __restrict__ wo,
                                                u16* __restrict__ xb, u16* __restrict__ wqb,
                                                u16* __restrict__ wkb, u16* __restrict__ wvb,
                                                u16* __restrict__ wob) {
    int bid = blockIdx.x;
    const float* src; u16* dst; int off;
    if (bid < NB_X)                       { src = x;  dst = xb;  off = bid * 1024; }
    else if (bid < NB_X + NB_QO)          { src = wq; dst = wqb; off = (bid - NB_X) * 1024; }
    else if (bid < NB_X + NB_QO + NB_KV)  { src = wk; dst = wkb; off = (bid - NB_X - NB_QO) * 1024; }
    else if (bid < NB_X + NB_QO + 2*NB_KV){ src = wv; dst = wvb; off = (bid - NB_X - NB_QO - NB_KV) * 1024; }
    else                                  { src = wo; dst = wob; off = (bid - NB_X - NB_QO - 2*NB_KV) * 1024; }
    int i = off + threadIdx.x * 4;
    float4 v = *(const float4*)&src[i];
    ushort4 o;
    o.x = f2bf(v.x); o.y = f2bf(v.y); o.z = f2bf(v.z); o.w = f2bf(v.w);
    *(ushort4*)&dst[i] = o;
}

// ---------------------------------------------------------------------------
// m97-structure MFMA GEMM: C[M,N] = A[M,K] @ B[N,K]^T, bf16 in, fp32 acc.
// MODE 0: fp32 row-major C
// MODE 5: fused QKV epilogue (B = [Wq;Wk;Wv] concat, N=3072):
//   n<2048      -> Qg bf16 [M][2048], scaled by QSCALE
//   2048..2559  -> Kg bf16 [M][512]
//   2560..3071  -> Vt bf16 [(b*KVN + d)][S]
// ---------------------------------------------------------------------------
template <int MODE>
__global__ __launch_bounds__(256) void gemm_mfma(const u16* __restrict__ A,
                                                 const u16* __restrict__ B,
                                                 void* __restrict__ Cv,
                                                 void* __restrict__ Cv2,
                                                 void* __restrict__ Cv3,
                                                 int M, int N, int K) {
    __shared__ __align__(16) u16 As[128 * 32];
    __shared__ __align__(16) u16 Bs[128 * 32];
    const int tid  = threadIdx.x;
    const int w    = tid >> 6;
    const int lane = tid & 63;
    const int l16  = lane & 15;
    const int quad = lane >> 4;
    const int wm = (w >> 1) * 64;
    const int wn = (w & 1) * 64;
    const int m0 = blockIdx.y * 128;
    const int n0 = blockIdx.x * 128;

    const int r0 = tid >> 2,           ko0 = (tid & 3) * 8;
    const int r1 = (256 + tid) >> 2,   ko1 = (tid & 3) * 8;
    u16* ldsA0 = &As[(size_t)(w * 64) * 8];
    u16* ldsA1 = &As[(size_t)(256 + w * 64) * 8];
    u16* ldsB0 = &Bs[(size_t)(w * 64) * 8];
    u16* ldsB1 = &Bs[(size_t)(256 + w * 64) * 8];

    f32x4 acc[4][4];
#pragma unroll
    for (int i = 0; i < 4; ++i)
#pragma unroll
        for (int j = 0; j < 4; ++j) acc[i][j] = (f32x4){0.f, 0.f, 0.f, 0.f};

    for (int k0 = 0; k0 < K; k0 += 32) {
        __syncthreads();
        gload_lds16(A + (size_t)(m0 + r0) * K + k0 + ko0, ldsA0);
        gload_lds16(A + (size_t)(m0 + r1) * K + k0 + ko1, ldsA1);
        gload_lds16(B + (size_t)(n0 + r0) * K + k0 + ko0, ldsB0);
        gload_lds16(B + (size_t)(n0 + r1) * K + k0 + ko1, ldsB1);
        __syncthreads();

        bf16x8 af[4], bfr[4];
#pragma unroll
        for (int i = 0; i < 4; ++i)
            af[i] = *(const bf16x8*)&As[(wm + i * 16 + l16) * 32 + quad * 8];
#pragma unroll
        for (int j = 0; j < 4; ++j)
            bfr[j] = *(const bf16x8*)&Bs[(wn + j * 16 + l16) * 32 + quad * 8];
#pragma unroll
        for (int i = 0; i < 4; ++i)
#pragma unroll
            for (int j = 0; j < 4; ++j)
                acc[i][j] = __builtin_amdgcn_mfma_f32_16x16x32_bf16(af[i], bfr[j], acc[i][j], 0, 0, 0);
    }

    if (MODE == 0) {
        float* C = (float*)Cv;
#pragma unroll
        for (int i = 0; i < 4; ++i)
#pragma unroll
            for (int j = 0; j < 4; ++j)
#pragma unroll
                for (int reg = 0; reg < 4; ++reg)
                    C[(size_t)(m0 + wm + i * 16 + quad * 4 + reg) * N + n0 + wn + j * 16 + l16] =
                        acc[i][j][reg];
    } else {   // MODE 5
        if (n0 < 2048) {
            u16* C = (u16*)Cv;   // Qg [M][2048], QSCALE folded in
#pragma unroll
            for (int i = 0; i < 4; ++i)
#pragma unroll
                for (int j = 0; j < 4; ++j)
#pragma unroll
                    for (int reg = 0; reg < 4; ++reg)
                        C[(size_t)(m0 + wm + i * 16 + quad * 4 + reg) * 2048 + n0 + wn + j * 16 + l16] =
                            f2bf(acc[i][j][reg] * QSCALE);
        } else if (n0 < 2560) {
            u16* C = (u16*)Cv2;  // Kg [M][512]
            const int nb = n0 - 2048;
#pragma unroll
            for (int i = 0; i < 4; ++i)
#pragma unroll
                for (int j = 0; j < 4; ++j)
#pragma unroll
                    for (int reg = 0; reg < 4; ++reg)
                        C[(size_t)(m0 + wm + i * 16 + quad * 4 + reg) * KVN + nb + wn + j * 16 + l16] =
                            f2bf(acc[i][j][reg]);
        } else {
            u16* C2 = (u16*)Cv3;  // Vt [(b*KVN + d)][S]
            const int db = n0 - 2560;
#pragma unroll
            for (int i = 0; i < 4; ++i) {
                const int m = m0 + wm + i * 16 + quad * 4;
                const int bb = m >> 11;
                const int s  = m & (SS - 1);
#pragma unroll
                for (int j = 0; j < 4; ++j) {
                    const int d = db + wn + j * 16 + l16;
                    ushort4 p;
                    p.x = f2bf(acc[i][j][0]); p.y = f2bf(acc[i][j][1]);
                    p.z = f2bf(acc[i][j][2]); p.w = f2bf(acc[i][j][3]);
                    *(ushort4*)&C2[((size_t)(bb * KVN + d)) * SS + s] = p;
                }
            }
        }
    }
}

// ---------------------------------------------------------------------------
// Flash-style causal GQA attention, bf16 MFMA, Q-tile 128 rows.
// IN-BLOCK SPLIT-K: 512 threads = 2 wave-groups of 4 waves. Group 0 handles
// keys [0,(qc+1)*64), group 1 keys [(qc+1)*64,(2qc+2)*64) -- both exactly
// qc+1 k-tiles (equal barrier counts). This HALVES the serial tile chain
// (the round-2 bottleneck: latency-bound at ~1 wave/SIMD, 6.6K cyc/tile)
// and keeps 2 waves/SIMD active for the whole kernel. Partials merged
// in-block at the end via LDS (flash merge), no workspace traffic.
// LDS: K dbuf 2grp*2*16K + V single 2grp*16K + P 2grp*16K = 128 KB ->
// 1 block/CU, 8 waves. V single-buffering is safe: its DMA (issued at tile
// top) is drained by the mid-tile __syncthreads (B2, also needed for
// cross-wave V visibility), a full QK+softmax phase after issue.
// Per-CU schedule self-balances: round-1 blocks sized 1..8 tiles, round-2
// 16..9; early-finishing CUs pick up the biggest queued blocks -> ~17
// serial tile-steps everywhere (vs 32 before).
// ---------------------------------------------------------------------------
__global__ __launch_bounds__(512, 2) void attn_mfma(const u16* __restrict__ Qg,
                                                    const u16* __restrict__ Kg,
                                                    const u16* __restrict__ VtG,
                                                    u16* __restrict__ ctx) {
    __shared__ __align__(16) u16 Ks[2][2][64 * 128];   // [grp][buf] 64 KB
    __shared__ __align__(16) u16 Vt[2][128 * 64];      // [grp] 32 KB
    __shared__ __align__(16) u16 Ps[2][128 * 64];      // [grp] 32 KB

    const int tid  = threadIdx.x;        // 0..511
    const int w    = tid >> 6;           // 0..7
    const int grp  = w >> 2;             // wave-group: 0 = low keys, 1 = high keys
    const int wq   = w & 3;              // q-row wave within group
    const int tg   = tid & 255;          // tid within group
    const int lane = tid & 63;
    const int l16  = lane & 15;
    const int quad = lane >> 4;
    const int sw   = l16 & 7;            // swizzle key for all fragment rows

    // task map: blocks f and f+256 get qc summing to 15 (small first, then big)
    const int f    = blockIdx.x;
    const int half = f >> 8;
    const int u    = f & 255;
    const int h    = u & 15;
    const int w2   = u >> 4;
    const int b    = w2 & 1;
    const int j    = w2 >> 1;                  // 0..7
    const int qc   = half ? (15 - j) : j;      // 0..15
    const int kvh  = h / GG;
    const int q0   = qc * 128;
    const int NT   = qc + 1;                   // k-tiles per group (equal!)

    const size_t kgbase = (size_t)(b * SS) * KVN + kvh * DD;
    const size_t vgbase = (size_t)(b * KVN + kvh * DD) * SS;

    const int myq[2] = { q0 + wq * 16 + l16, q0 + 64 + wq * 16 + l16 };

    // ---- Q fragments direct from global ----
    bf16x8 Qa[2][4];
#pragma unroll
    for (int mi = 0; mi < 2; ++mi)
#pragma unroll
        for (int kd = 0; kd < 4; ++kd)
            Qa[mi][kd] = *(const bf16x8*)(Qg + (size_t)(b * SS + myq[mi]) * EE
                                          + h * DD + kd * 32 + quad * 8);

    float m_i[2] = {-INFINITY, -INFINITY};
    float l_i[2] = {0.f, 0.f};          // per-lane partials, reduced at the end
    f32x4 acc_o[2][8];
#pragma unroll
    for (int mi = 0; mi < 2; ++mi)
#pragma unroll
        for (int dt = 0; dt < 8; ++dt) acc_o[mi][dt] = (f32x4){0.f, 0.f, 0.f, 0.f};

    // ---- swizzled async stages (per group, 4 waves each) ----
    auto stageK = [&](int gkt, int buf) {
#pragma unroll
        for (int it = 0; it < 4; ++it) {
            int ci = it * 256 + tg;           // chunk slot (16B units), 1024 total
            int r = ci >> 4, pp = ci & 15;
            int c = (pp & 8) | ((pp ^ r) & 7);
            gload_lds16(Kg + kgbase + (size_t)(gkt * 64 + r) * KVN + c * 8,
                        &Ks[grp][buf][(size_t)(it * 256 + (tg & 192)) * 8]);
        }
    };
    auto stageV = [&](int gkt) {
#pragma unroll
        for (int it = 0; it < 4; ++it) {
            int ci = it * 256 + tg;
            int r = ci >> 3, pp = ci & 7;
            int c = (pp ^ r) & 7;
            gload_lds16(VtG + vgbase + (size_t)r * SS + gkt * 64 + c * 8,
                        &Vt[grp][(size_t)(it * 256 + (tg & 192)) * 8]);
        }
    };

    stageK(grp * NT, 0);
    int buf = 0;

    for (int kt = 0; kt < NT; ++kt) {
        const int gkt = grp * NT + kt;        // global 64-key tile index
        const int gk0 = gkt * 64;             // first key of this tile

        __syncthreads();                      // B1: K(kt) landed; V region free
        stageV(gkt);
        if (kt + 1 < NT) stageK(gkt + 1, buf ^ 1);

        // per-mi status (wave-uniform): fully-masked / diagonal
        bool skip[2], diag[2];
#pragma unroll
        for (int mi = 0; mi < 2; ++mi) {
            const int lo = q0 + mi * 64;
            skip[mi] = (gk0 > lo + 63);
            diag[mi] = (!skip[mi]) && (gk0 + 63 > lo);
        }

        const u16* kb_base = Ks[grp][buf];

        // ---- S^T = K Q^T : lane q=l16, k = gk0 + kkt*16 + quad*4 + reg ----
        f32x4 sc[2][4];
#pragma unroll
        for (int mi = 0; mi < 2; ++mi)
#pragma unroll
            for (int kkt = 0; kkt < 4; ++kkt) sc[mi][kkt] = (f32x4){0.f, 0.f, 0.f, 0.f};
        __builtin_amdgcn_s_setprio(1);
#pragma unroll
        for (int kkt = 0; kkt < 4; ++kkt) {
            const int R = kkt * 16 + l16;
            bf16x8 kb[4];
#pragma unroll
            for (int kd = 0; kd < 4; ++kd) {
                int c = kd * 4 + quad;
                int pp = (c & 8) | ((c ^ sw) & 7);
                kb[kd] = *(const bf16x8*)&kb_base[(R * 16 + pp) * 8];
            }
            if (!skip[1])
#pragma unroll
                for (int kd = 0; kd < 4; ++kd)
                    sc[1][kkt] = __builtin_amdgcn_mfma_f32_16x16x32_bf16(kb[kd], Qa[1][kd], sc[1][kkt], 0, 0, 0);
            if (!skip[0])
#pragma unroll
                for (int kd = 0; kd < 4; ++kd)
                    sc[0][kkt] = __builtin_amdgcn_mfma_f32_16x16x32_bf16(kb[kd], Qa[0][kd], sc[0][kkt], 0, 0, 0);
        }
        __builtin_amdgcn_s_setprio(0);

        // ---- per-lane online softmax (log2 domain), vote-gated rescale ----
#pragma unroll
        for (int mi = 0; mi < 2; ++mi) {
            if (skip[mi]) continue;
            if (diag[mi]) {
                const int kb0 = gk0 + quad * 4;
#pragma unroll
                for (int kkt = 0; kkt < 4; ++kkt)
#pragma unroll
                    for (int reg = 0; reg < 4; ++reg)
                        if (kb0 + kkt * 16 + reg > myq[mi]) sc[mi][kkt][reg] = -INFINITY;
            }
            float rowmax = -INFINITY;
#pragma unroll
            for (int kkt = 0; kkt < 4; ++kkt)
                rowmax = fmaxf(rowmax,
                               fmaxf(fmaxf(sc[mi][kkt][0], sc[mi][kkt][1]),
                                     fmaxf(sc[mi][kkt][2], sc[mi][kkt][3])));

            if (__any(rowmax > m_i[mi] + 8.0f)) {   // wave-uniform, rare after warmup
                float gmax = fmaxf(rowmax, __shfl_xor(rowmax, 16, 64));
                gmax = fmaxf(gmax, __shfl_xor(gmax, 32, 64));
                float mnew = fmaxf(m_i[mi], gmax);
                float al = exp2f(m_i[mi] - mnew);
                m_i[mi] = mnew;
                l_i[mi] *= al;
#pragma unroll
                for (int dt = 0; dt < 8; ++dt)
#pragma unroll
                    for (int reg = 0; reg < 4; ++reg)
                        acc_o[mi][dt][reg] *= al;
            }

            float rsum = 0.f;
#pragma unroll
            for (int kkt = 0; kkt < 4; ++kkt)
#pragma unroll
                for (int reg = 0; reg < 4; ++reg) {
                    float p = exp2f(sc[mi][kkt][reg] - m_i[mi]);   // bounded by 2^8
                    sc[mi][kkt][reg] = p;
                    rsum += p;
                }
            l_i[mi] += rsum;

            // swizzled packed P^T write via HW cvt_pk
            const int prow = mi * 64 + wq * 16 + l16;
#pragma unroll
            for (int kkt = 0; kkt < 4; ++kkt) {
                int ch = (kkt * 2 + (quad >> 1)) ^ sw;
                uint2 pk;
                pk.x = cvtpk_bf16(sc[mi][kkt][0], sc[mi][kkt][1]);
                pk.y = cvtpk_bf16(sc[mi][kkt][2], sc[mi][kkt][3]);
                *(uint2*)&Ps[grp][(prow * 8 + ch) * 8 + (quad & 1) * 4] = pk;
            }
        }

        __syncthreads();                      // B2: V(kt) landed (all waves' DMA)

        // ---- O^T += V^T P^T ----
        const u16* vb_base = Vt[grp];
        __builtin_amdgcn_s_setprio(1);
#pragma unroll
        for (int ks = 0; ks < 2; ++ks) {
            const int pc = (ks * 4 + quad) ^ sw;
            bf16x8 pb1, pb0;
            if (!skip[1]) pb1 = *(const bf16x8*)&Ps[grp][((64 + wq * 16 + l16) * 8 + pc) * 8];
            if (!skip[0]) pb0 = *(const bf16x8*)&Ps[grp][((wq * 16 + l16) * 8 + pc) * 8];
#pragma unroll
            for (int dt = 0; dt < 8; ++dt) {
                bf16x8 va = *(const bf16x8*)&vb_base[((dt * 16 + l16) * 8 + pc) * 8];
                if (!skip[1])
                    acc_o[1][dt] = __builtin_amdgcn_mfma_f32_16x16x32_bf16(va, pb1, acc_o[1][dt], 0, 0, 0);
                if (!skip[0])
                    acc_o[0][dt] = __builtin_amdgcn_mfma_f32_16x16x32_bf16(va, pb0, acc_o[0][dt], 0, 0, 0);
            }
        }
        __builtin_amdgcn_s_setprio(0);
        buf ^= 1;
    }

    // ---- in-block flash merge of the two key-halves ----
    __syncthreads();                          // B3: all compute done; LDS free
    float* dumpO = (float*)&Ks[0][0][0];      // 4 waves * 64 lanes * 64 f32 = 64 KB
    float* dumpML = (float*)&Ps[1][0];        // 4 waves * 64 lanes * 4 f32 = 4 KB
    if (grp == 1) {
        const int base = (wq * 64 + lane) * 64;
#pragma unroll
        for (int mi = 0; mi < 2; ++mi)
#pragma unroll
            for (int dt = 0; dt < 8; ++dt)
                *(f32x4*)&dumpO[base + mi * 32 + dt * 4] = acc_o[mi][dt];
        const int mb = (wq * 64 + lane) * 4;
        dumpML[mb + 0] = m_i[0];
        dumpML[mb + 1] = m_i[1];
        dumpML[mb + 2] = l_i[0];
        dumpML[mb + 3] = l_i[1];
    }
    __syncthreads();                          // B4: dump visible
    if (grp == 0) {
        const int base = (wq * 64 + lane) * 64;
        const int mb = (wq * 64 + lane) * 4;
#pragma unroll
        for (int mi = 0; mi < 2; ++mi) {
            const float m1 = dumpML[mb + mi];
            const float l1 = dumpML[mb + 2 + mi];
            const float ms = fmaxf(m_i[mi], m1);
            const float a0 = exp2f(m_i[mi] - ms);   // 0 if m_i = -inf
            const float a1 = exp2f(m1 - ms);        // 0 if m1  = -inf
            float lt = l_i[mi] * a0 + l1 * a1;
            lt += __shfl_xor(lt, 16, 64);
            lt += __shfl_xor(lt, 32, 64);
            const float linv = 1.f / lt;
            u16* dst = ctx + (size_t)(b * SS + myq[mi]) * EE + h * DD;
#pragma unroll
            for (int dt = 0; dt < 8; ++dt) {
                f32x4 o1 = *(const f32x4*)&dumpO[base + mi * 32 + dt * 4];
                uint2 o;
                o.x = cvtpk_bf16((acc_o[mi][dt][0] * a0 + o1[0] * a1) * linv,
                                 (acc_o[mi][dt][1] * a0 + o1[1] * a1) * linv);
                o.y = cvtpk_bf16((acc_o[mi][dt][2] * a0 + o1[2] * a1) * linv,
                                 (acc_o[mi][dt][3] * a0 + o1[3] * a1) * linv);
                *(uint2*)&dst[dt * 16 + quad * 4] = o;
            }
        }
    }
}

// ---------------------------------------------------------------------------
extern "C" void kernel_launch(void* const* d_in, const int* in_sizes, int n_in,
                              void* d_out, int out_size, void* d_ws, size_t ws_size,
                              hipStream_t stream) {
    const float* x  = (const float*)d_in[0];
    const float* Wq = (const float*)d_in[1];
    const float* Wk = (const float*)d_in[2];
    const float* Wv = (const float*)d_in[3];
    const float* Wo = (const float*)d_in[4];
    float* out = (float*)d_out;

    const int M = BB * SS;                        // 4096
    u16* xb  = (u16*)d_ws;                        // M*E
    u16* Wqb = xb  + (size_t)M * EE;              // E*E   } contiguous ->
    u16* Wkb = Wqb + (size_t)EE * EE;             // KVN*E }  single 3072-row
    u16* Wvb = Wkb + (size_t)KVN * EE;            // KVN*E }  B matrix
    u16* Wob = Wvb + (size_t)KVN * EE;            // E*E
    u16* Qg  = Wob + (size_t)EE * EE;             // M*E (pre-scaled by QSCALE)
    u16* Kg  = Qg  + (size_t)M * EE;              // M*KVN
    u16* VtG = Kg  + (size_t)M * KVN;             // M*KVN (transposed)
    u16* ctx = VtG + (size_t)M * KVN;             // M*E

    dim3 blk(256);
    cast_all<<<dim3(NB_X + NB_QO + 2 * NB_KV + NB_QO), blk, 0, stream>>>(
        x, Wq, Wk, Wv, Wo, xb, Wqb, Wkb, Wvb, Wob);

    // fused QKV projection: B = [Wq;Wk;Wv] (3072 x 2048)
    gemm_mfma<5><<<dim3(3072 / 128, M / 128), blk, 0, stream>>>(
        xb, Wqb, Qg, Kg, VtG, M, 3072, EE);
    attn_mfma<<<dim3(512), dim3(512), 0, stream>>>(Qg, Kg, VtG, ctx);
    gemm_mfma<0><<<dim3(EE / 128, M / 128), blk, 0, stream>>>(
        ctx, Wob, out, nullptr, nullptr, M, EE, EE);
}